// Round 1
// baseline (3827.189 us; speedup 1.0000x reference)
//
#include <hip/hip_runtime.h>
#include <math.h>

#define N_NODES 50000
#define N_EDGES 800000
#define CDIM 64
#define MCDIM 128

#define XSTRIDE 200   // edge_input row stride (196 + pad, 16B-aligned rows)
#define HSTRIDE 132   // hidden row stride (128 + pad)
#define USTRIDE 260   // update_input row stride (256 + pad)

__device__ __forceinline__ float gelu_exact(float x) {
    return 0.5f * x * (1.0f + erff(x * 0.70710678118654752f));
}

// ---------------------------------------------------------------------------
// Register-tiled GEMM over a 64-row LDS tile: Y[e][c] for e in [ty*4, ty*4+4),
// c in [tx*8, tx*8+8).  X is LDS [64][xstride], W is global [K][128] row-major.
// ---------------------------------------------------------------------------
template <int K, bool GELU>
__device__ __forceinline__ void gemm128(const float* Xl, int xstride,
                                        const float* __restrict__ W,
                                        const float* __restrict__ bias,
                                        float* Yl, int ystride, int tx, int ty) {
    float acc[4][8];
#pragma unroll
    for (int i = 0; i < 4; i++)
#pragma unroll
        for (int j = 0; j < 8; j++) acc[i][j] = 0.0f;

    const float* xb = Xl + (ty * 4) * xstride;
#pragma unroll 2
    for (int k = 0; k < K; k++) {
        float xv[4];
        xv[0] = xb[k];
        xv[1] = xb[xstride + k];
        xv[2] = xb[2 * xstride + k];
        xv[3] = xb[3 * xstride + k];
        float4 wa = *(const float4*)(W + k * 128 + tx * 8);
        float4 wb = *(const float4*)(W + k * 128 + tx * 8 + 4);
        float wv[8] = {wa.x, wa.y, wa.z, wa.w, wb.x, wb.y, wb.z, wb.w};
#pragma unroll
        for (int i = 0; i < 4; i++)
#pragma unroll
            for (int j = 0; j < 8; j++) acc[i][j] += xv[i] * wv[j];
    }
#pragma unroll
    for (int i = 0; i < 4; i++) {
        float* yrow = Yl + (ty * 4 + i) * ystride + tx * 8;
#pragma unroll
        for (int j = 0; j < 8; j++) {
            float v = acc[i][j] + bias[tx * 8 + j];
            if (GELU) v = gelu_exact(v);
            yrow[j] = v;
        }
    }
}

// ---------------------------------------------------------------------------
// LayerNorm over C=64 per node (one wave per node), + block-partial global sum,
// + flow_dir normalization (block 0).
// ---------------------------------------------------------------------------
__global__ __launch_bounds__(256) void ln_kernel(
    const float* __restrict__ h, const float* __restrict__ ln_g,
    const float* __restrict__ ln_b, const float* __restrict__ flow_dir,
    float* __restrict__ feat, float* __restrict__ gsum, float* __restrict__ u_out) {
    int t = threadIdx.x;
    int ln = t >> 6;  // node within block (0..3)
    int c = t & 63;
    int n = blockIdx.x * 4 + ln;

    float x = h[n * CDIM + c];
    float s = x;
#pragma unroll
    for (int off = 32; off > 0; off >>= 1) s += __shfl_xor(s, off, 64);
    float mu = s * (1.0f / 64.0f);
    float d = x - mu;
    float v = d * d;
#pragma unroll
    for (int off = 32; off > 0; off >>= 1) v += __shfl_xor(v, off, 64);
    float rs = 1.0f / sqrtf(v * (1.0f / 64.0f) + 1e-5f);
    float f = d * rs * ln_g[c] + ln_b[c];
    feat[n * CDIM + c] = f;

    __shared__ float fs[4][64];
    fs[ln][c] = f;
    __syncthreads();
    if (t < 64) {
        float p = fs[0][t] + fs[1][t] + fs[2][t] + fs[3][t];
        atomicAdd(&gsum[t], p);
    }
    if (blockIdx.x == 0 && t == 0) {
        float ux = flow_dir[0], uy = flow_dir[1], uz = flow_dir[2];
        float nrm = sqrtf(ux * ux + uy * uy + uz * uz) + 1e-8f;
        u_out[0] = ux / nrm;
        u_out[1] = uy / nrm;
        u_out[2] = uz / nrm;
    }
}

// ---------------------------------------------------------------------------
// Fused edge pipeline: stage edge_input -> 3-layer edge MLP -> gate -> scatter
// 64 edges per 256-thread block.
// ---------------------------------------------------------------------------
struct SmemEdge {
    union {
        float xs[64 * XSTRIDE];   // 51200 B : edge_input [e][196]
        float hs2[64 * HSTRIDE];  // 33792 B : h2 / g1 (xs dead after GEMM1)
    } a;
    float hs1[64 * HSTRIDE];      // h1 / h3
    float gate[64];
    int rows[64];
};

__global__ __launch_bounds__(256) void edge_kernel(
    const float* __restrict__ coords, const int* __restrict__ eidx,
    const float* __restrict__ feat, const float* __restrict__ u,
    const float* __restrict__ ew1, const float* __restrict__ eb1,
    const float* __restrict__ ew2, const float* __restrict__ eb2,
    const float* __restrict__ ew3, const float* __restrict__ eb3,
    const float* __restrict__ gw1, const float* __restrict__ gb1,
    const float* __restrict__ gw2, const float* __restrict__ gb2,
    float* __restrict__ agg, float* __restrict__ deg) {
    __shared__ SmemEdge sm;
    int t = threadIdx.x;
    int e0 = blockIdx.x * 64;

    {   // stage edge_input: 4 threads per edge
        int le = t >> 2, sub = t & 3;
        int e = e0 + le;
        int row = eidx[e];
        int col = eidx[N_EDGES + e];
        const float4* fi4 = (const float4*)(feat + row * CDIM);
        const float4* fj4 = (const float4*)(feat + col * CDIM);
        float* xr = sm.a.xs + le * XSTRIDE;
#pragma unroll
        for (int i = 0; i < 4; i++) {
            int c = sub * 16 + i * 4;
            float4 a = fi4[c >> 2];
            float4 b = fj4[c >> 2];
            *(float4*)(xr + c) = a;
            *(float4*)(xr + 64 + c) = b;
            float4 dd;
            dd.x = a.x - b.x; dd.y = a.y - b.y; dd.z = a.z - b.z; dd.w = a.w - b.w;
            *(float4*)(xr + 128 + c) = dd;
        }
        if (sub == 0) {
            sm.rows[le] = row;
            float xix = coords[row * 3], xiy = coords[row * 3 + 1], xiz = coords[row * 3 + 2];
            float xjx = coords[col * 3], xjy = coords[col * 3 + 1], xjz = coords[col * 3 + 2];
            float rx = xix - xjx, ry = xiy - xjy, rz = xiz - xjz;
            float ux = u[0], uy = u[1], uz = u[2];
            xr[192] = rx * rx + ry * ry + rz * rz;
            xr[193] = xix * ux + xiy * uy + xiz * uz;
            xr[194] = xjx * ux + xjy * uy + xjz * uz;
            xr[195] = rx * ux + ry * uy + rz * uz;
            atomicAdd(&deg[row], 1.0f);
        }
    }
    __syncthreads();

    int tx = t & 15, ty = t >> 4;
    gemm128<196, true>(sm.a.xs, XSTRIDE, ew1, eb1, sm.hs1, HSTRIDE, tx, ty);   // h1
    __syncthreads();
    gemm128<128, true>(sm.hs1, HSTRIDE, ew2, eb2, sm.a.hs2, HSTRIDE, tx, ty);  // h2
    __syncthreads();
    gemm128<128, false>(sm.a.hs2, HSTRIDE, ew3, eb3, sm.hs1, HSTRIDE, tx, ty); // h3 = edge_hidden
    __syncthreads();
    gemm128<128, true>(sm.hs1, HSTRIDE, gw1, gb1, sm.a.hs2, HSTRIDE, tx, ty);  // g1
    __syncthreads();

    {   // gate[e] = sigmoid(g1[e] . gw2 + gb2) ; 4 threads per edge
        int le = t >> 2, sub = t & 3;
        const float* gr = sm.a.hs2 + le * HSTRIDE + sub * 32;
        float p = 0.0f;
#pragma unroll 8
        for (int k = 0; k < 32; k++) p += gr[k] * gw2[sub * 32 + k];
        p += __shfl_down(p, 1, 64);
        p += __shfl_down(p, 2, 64);
        if (sub == 0) {
            float z = p + gb2[0];
            sm.gate[le] = 1.0f / (1.0f + expf(-z));
        }
    }
    __syncthreads();

    // scatter msg = gate * h3 into agg[row]
#pragma unroll
    for (int i = 0; i < 4; i++) {
        int e = ty * 4 + i;
        int row = sm.rows[e];
        float g = sm.gate[e];
        float* agr = agg + (long)row * MCDIM;
        const float* h3 = sm.hs1 + e * HSTRIDE;
#pragma unroll
        for (int j = 0; j < 8; j++) {
            int c = tx + 16 * j;  // consecutive lanes -> consecutive c (coalesced)
            atomicAdd(agr + c, g * h3[c]);
        }
    }
}

// ---------------------------------------------------------------------------
// Global-context MLP (1 block, 64 threads) + tanh(res_scale)
// ---------------------------------------------------------------------------
__global__ void global_kernel(const float* __restrict__ gsum,
                              const float* __restrict__ glw1, const float* __restrict__ glb1,
                              const float* __restrict__ glw2, const float* __restrict__ glb2,
                              const float* __restrict__ glw3, const float* __restrict__ glb3,
                              const float* __restrict__ res_scale,
                              float* __restrict__ gctx, float* __restrict__ tres) {
    __shared__ float a[64], b[64];
    int t = threadIdx.x;
    a[t] = gsum[t] * (1.0f / (float)N_NODES);
    __syncthreads();
    float s = glb1[t];
    for (int k = 0; k < 64; k++) s += a[k] * glw1[k * 64 + t];
    b[t] = gelu_exact(s);
    __syncthreads();
    s = glb2[t];
    for (int k = 0; k < 64; k++) s += b[k] * glw2[k * 64 + t];
    __syncthreads();
    a[t] = gelu_exact(s);
    __syncthreads();
    s = glb3[t];
    for (int k = 0; k < 64; k++) s += a[k] * glw3[k * 64 + t];
    gctx[t] = s;
    if (t == 0) *tres = tanhf(res_scale[0]);
}

// ---------------------------------------------------------------------------
// Fused node update: [feat | agg/deg | gctx] -> 3-layer MLP -> *tanh(res)
// 64 nodes per 256-thread block.
// ---------------------------------------------------------------------------
struct SmemUpd {
    union {
        float ui[64 * USTRIDE];   // 66560 B
        float hs2[64 * HSTRIDE];
    } a;
    float hs1[64 * HSTRIDE];
};

__global__ __launch_bounds__(256) void update_kernel(
    const float* __restrict__ feat, const float* __restrict__ agg,
    const float* __restrict__ deg, const float* __restrict__ gctx,
    const float* __restrict__ tres,
    const float* __restrict__ uw1, const float* __restrict__ ub1,
    const float* __restrict__ uw2, const float* __restrict__ ub2,
    const float* __restrict__ uw3, const float* __restrict__ ub3,
    float* __restrict__ out) {
    __shared__ SmemUpd sm;
    int t = threadIdx.x;
    int n0 = blockIdx.x * 64;

    {   // stage update_input: 4 threads per node, 64 floats each
        int ln = t >> 2, sub = t & 3;
        int n = n0 + ln;
        float* ur = sm.a.ui + ln * USTRIDE;
        if (n < N_NODES) {
            if (sub == 0) {
                const float4* f4 = (const float4*)(feat + n * CDIM);
#pragma unroll
                for (int m = 0; m < 16; m++) *(float4*)(ur + m * 4) = f4[m];
            } else if (sub == 3) {
                const float4* g4 = (const float4*)gctx;
#pragma unroll
                for (int m = 0; m < 16; m++) *(float4*)(ur + 192 + m * 4) = g4[m];
            } else {
                float inv = 1.0f / fmaxf(deg[n], 1.0f);
                const float4* a4 = (const float4*)(agg + (long)n * MCDIM + (sub - 1) * 64);
                float* dst = ur + sub * 64;
#pragma unroll
                for (int m = 0; m < 16; m++) {
                    float4 v = a4[m];
                    v.x *= inv; v.y *= inv; v.z *= inv; v.w *= inv;
                    *(float4*)(dst + m * 4) = v;
                }
            }
        } else {
            float4 z = {0.0f, 0.0f, 0.0f, 0.0f};
#pragma unroll
            for (int m = 0; m < 16; m++) *(float4*)(ur + sub * 64 + m * 4) = z;
        }
    }
    __syncthreads();

    int tx = t & 15, ty = t >> 4;
    gemm128<256, true>(sm.a.ui, USTRIDE, uw1, ub1, sm.hs1, HSTRIDE, tx, ty);   // h1
    __syncthreads();
    gemm128<128, true>(sm.hs1, HSTRIDE, uw2, ub2, sm.a.hs2, HSTRIDE, tx, ty);  // h2
    __syncthreads();

    {   // layer 3: 128 -> 64, fused scale + store
        float acc[4][4];
#pragma unroll
        for (int i = 0; i < 4; i++)
#pragma unroll
            for (int j = 0; j < 4; j++) acc[i][j] = 0.0f;
        const float* xb = sm.a.hs2 + (ty * 4) * HSTRIDE;
#pragma unroll 2
        for (int k = 0; k < 128; k++) {
            float xv[4];
            xv[0] = xb[k];
            xv[1] = xb[HSTRIDE + k];
            xv[2] = xb[2 * HSTRIDE + k];
            xv[3] = xb[3 * HSTRIDE + k];
            float4 w = *(const float4*)(uw3 + k * 64 + tx * 4);
#pragma unroll
            for (int i = 0; i < 4; i++) {
                acc[i][0] += xv[i] * w.x;
                acc[i][1] += xv[i] * w.y;
                acc[i][2] += xv[i] * w.z;
                acc[i][3] += xv[i] * w.w;
            }
        }
        float tr = *tres;
        float4 bv = *(const float4*)(ub3 + tx * 4);
#pragma unroll
        for (int i = 0; i < 4; i++) {
            int n = n0 + ty * 4 + i;
            if (n < N_NODES) {
                float4 o;
                o.x = (acc[i][0] + bv.x) * tr;
                o.y = (acc[i][1] + bv.y) * tr;
                o.z = (acc[i][2] + bv.z) * tr;
                o.w = (acc[i][3] + bv.w) * tr;
                *(float4*)(out + (long)n * CDIM + tx * 4) = o;
            }
        }
    }
}

// ---------------------------------------------------------------------------
extern "C" void kernel_launch(void* const* d_in, const int* in_sizes, int n_in,
                              void* d_out, int out_size, void* d_ws, size_t ws_size,
                              hipStream_t stream) {
    const float* coords = (const float*)d_in[0];
    const float* h = (const float*)d_in[1];
    const float* flow = (const float*)d_in[2];
    const int* eidx = (const int*)d_in[3];
    const float* ln_g = (const float*)d_in[4];
    const float* ln_b = (const float*)d_in[5];
    const float* ew1 = (const float*)d_in[6];
    const float* eb1 = (const float*)d_in[7];
    const float* ew2 = (const float*)d_in[8];
    const float* eb2 = (const float*)d_in[9];
    const float* ew3 = (const float*)d_in[10];
    const float* eb3 = (const float*)d_in[11];
    const float* gw1 = (const float*)d_in[12];
    const float* gb1 = (const float*)d_in[13];
    const float* gw2 = (const float*)d_in[14];
    const float* gb2 = (const float*)d_in[15];
    const float* glw1 = (const float*)d_in[16];
    const float* glb1 = (const float*)d_in[17];
    const float* glw2 = (const float*)d_in[18];
    const float* glb2 = (const float*)d_in[19];
    const float* glw3 = (const float*)d_in[20];
    const float* glb3 = (const float*)d_in[21];
    const float* uw1 = (const float*)d_in[22];
    const float* ub1 = (const float*)d_in[23];
    const float* uw2 = (const float*)d_in[24];
    const float* ub2 = (const float*)d_in[25];
    const float* uw3 = (const float*)d_in[26];
    const float* ub3 = (const float*)d_in[27];
    const float* res = (const float*)d_in[28];

    float* ws = (float*)d_ws;
    float* agg = ws;                                 // N*128
    float* deg = agg + (size_t)N_NODES * MCDIM;      // N
    float* gsum = deg + N_NODES;                     // 64
    float* feat = gsum + 64;                         // N*64
    float* u = feat + (size_t)N_NODES * CDIM;        // 4
    float* gctx = u + 4;                             // 64
    float* tres = gctx + 64;                         // 1

    hipMemsetAsync(agg, 0, ((size_t)N_NODES * 129 + 64) * sizeof(float), stream);
    ln_kernel<<<N_NODES / 4, 256, 0, stream>>>(h, ln_g, ln_b, flow, feat, gsum, u);
    edge_kernel<<<N_EDGES / 64, 256, 0, stream>>>(coords, eidx, feat, u,
                                                  ew1, eb1, ew2, eb2, ew3, eb3,
                                                  gw1, gb1, gw2, gb2, agg, deg);
    global_kernel<<<1, 64, 0, stream>>>(gsum, glw1, glb1, glw2, glb2, glw3, glb3,
                                        res, gctx, tres);
    update_kernel<<<(N_NODES + 63) / 64, 256, 0, stream>>>(feat, agg, deg, gctx, tres,
                                                           uw1, ub1, uw2, ub2, uw3, ub3,
                                                           (float*)d_out);
}

// Round 2
// 1202.534 us; speedup vs baseline: 3.1826x; 3.1826x over previous
//
#include <hip/hip_runtime.h>
#include <math.h>

#define N_NODES 50000
#define N_EDGES 800000
#define CDIM 64
#define MCDIM 128

#define HSTRIDE 132   // fp32 hidden row stride (update kernel)
#define USTRIDE 260   // fp32 update_input row stride

// bf16 LDS strides (elements). Row stride in dwords must be == 4 (mod 32) to
// keep ds_read_b128 A-fragment loads conflict-free: 264*2B=132w, 136*2B=68w.
#define XS1 264       // edge_input, K padded 196 -> 224
#define HS  136       // hidden layers, K=128

typedef __attribute__((ext_vector_type(8))) short short8;
typedef __attribute__((ext_vector_type(4))) float floatx4;

__device__ __forceinline__ float gelu_exact(float x) {
    return 0.5f * x * (1.0f + erff(x * 0.70710678118654752f));
}

__device__ __forceinline__ unsigned short f2bf(float f) {  // RNE fp32->bf16
    unsigned int u = __float_as_uint(f);
    unsigned int r = u + 0x7fffu + ((u >> 16) & 1u);
    return (unsigned short)(r >> 16);
}

__device__ __forceinline__ ushort4 pack4(float4 v) {
    ushort4 r;
    r.x = f2bf(v.x); r.y = f2bf(v.y); r.z = f2bf(v.z); r.w = f2bf(v.w);
    return r;
}

// ---------------------------------------------------------------------------
// Weight fragment pre-swizzle: for each 16x16x32 MFMA B-fragment, lane l holds
// B[k = k0 + (l>>4)*8 + j][n = 16*ct + (l&15)], j=0..7, contiguous 16B/lane.
// Chunks: ew1 7 (K 196 zero-padded to 224), ew2 4, ew3 4, gw1 4  -> 19 total.
// ---------------------------------------------------------------------------
#define F1_OFF 0
#define F2_OFF (7 * 4096)
#define F3_OFF (11 * 4096)
#define FG_OFF (15 * 4096)
#define FRAG_TOTAL (19 * 4096)   // ushorts

__global__ __launch_bounds__(256) void prep_frags(
    const float* __restrict__ ew1, const float* __restrict__ ew2,
    const float* __restrict__ ew3, const float* __restrict__ gw1,
    unsigned short* __restrict__ frags) {
    int idx = blockIdx.x * 256 + threadIdx.x;
    if (idx >= FRAG_TOTAL) return;
    int chunk = idx >> 12;           // 0..18
    int rem = idx & 4095;
    int ct = rem >> 9;               // col tile 0..7
    int lane = (rem >> 3) & 63;
    int j = rem & 7;
    const float* W; int K; int kbase;
    if (chunk < 7)       { W = ew1; K = 196; kbase = chunk * 32; }
    else if (chunk < 11) { W = ew2; K = 128; kbase = (chunk - 7) * 32; }
    else if (chunk < 15) { W = ew3; K = 128; kbase = (chunk - 11) * 32; }
    else                 { W = gw1; K = 128; kbase = (chunk - 15) * 32; }
    int k = kbase + (lane >> 4) * 8 + j;
    int n = ct * 16 + (lane & 15);
    float v = (k < K) ? W[k * 128 + n] : 0.0f;
    frags[idx] = f2bf(v);
}

// ---------------------------------------------------------------------------
// MFMA helpers (per-wave 16-row tile x 128 cols)
// ---------------------------------------------------------------------------
template <int NCH>
__device__ __forceinline__ void mfma_layer(const unsigned short* Xl, int xs,
                                           const unsigned short* __restrict__ F,
                                           int lane, floatx4 acc[8]) {
    int q = lane >> 4, c = lane & 15;
    const unsigned short* xrow = Xl + c * xs + q * 8;
    for (int k0 = 0; k0 < NCH; k0++) {
        short8 a = *(const short8*)(xrow + k0 * 32);
#pragma unroll
        for (int ct = 0; ct < 8; ct++) {
            short8 b = *(const short8*)(F + ((k0 * 8 + ct) * 64 + lane) * 8);
            acc[ct] = __builtin_amdgcn_mfma_f32_16x16x32_bf16(a, b, acc[ct], 0, 0, 0);
        }
    }
}

// bias + (opt) gelu, store bf16 into next layer's A-layout LDS tile.
// C layout: value (ct,i) sits at row (lane>>4)*4+i, col 16*ct+(lane&15).
template <bool GELU>
__device__ __forceinline__ void epilogue_store(floatx4 acc[8],
                                               const float* __restrict__ bias,
                                               unsigned short* dst, int xs, int lane) {
    int q = lane >> 4, c = lane & 15;
#pragma unroll
    for (int ct = 0; ct < 8; ct++) {
        float b = bias[ct * 16 + c];
#pragma unroll
        for (int i = 0; i < 4; i++) {
            float v = acc[ct][i] + b;
            if (GELU) v = gelu_exact(v);
            dst[(q * 4 + i) * xs + ct * 16 + c] = f2bf(v);
        }
    }
}

// ---------------------------------------------------------------------------
// LayerNorm + global-mean partials + flow_dir normalize
// ---------------------------------------------------------------------------
__global__ __launch_bounds__(256) void ln_kernel(
    const float* __restrict__ h, const float* __restrict__ ln_g,
    const float* __restrict__ ln_b, const float* __restrict__ flow_dir,
    float* __restrict__ feat, float* __restrict__ gsum, float* __restrict__ u_out) {
    int t = threadIdx.x;
    int ln = t >> 6;
    int c = t & 63;
    int n = blockIdx.x * 4 + ln;

    float x = h[n * CDIM + c];
    float s = x;
#pragma unroll
    for (int off = 32; off > 0; off >>= 1) s += __shfl_xor(s, off, 64);
    float mu = s * (1.0f / 64.0f);
    float d = x - mu;
    float v = d * d;
#pragma unroll
    for (int off = 32; off > 0; off >>= 1) v += __shfl_xor(v, off, 64);
    float rs = 1.0f / sqrtf(v * (1.0f / 64.0f) + 1e-5f);
    float f = d * rs * ln_g[c] + ln_b[c];
    feat[n * CDIM + c] = f;

    __shared__ float fs[4][64];
    fs[ln][c] = f;
    __syncthreads();
    if (t < 64) {
        float p = fs[0][t] + fs[1][t] + fs[2][t] + fs[3][t];
        atomicAdd(&gsum[t], p);
    }
    if (blockIdx.x == 0 && t == 0) {
        float ux = flow_dir[0], uy = flow_dir[1], uz = flow_dir[2];
        float nrm = sqrtf(ux * ux + uy * uy + uz * uz) + 1e-8f;
        u_out[0] = ux / nrm;
        u_out[1] = uy / nrm;
        u_out[2] = uz / nrm;
    }
}

// ---------------------------------------------------------------------------
// Fused MFMA edge pipeline: 64 edges/block, 256 threads (4 waves of 16 rows).
// ---------------------------------------------------------------------------
struct SmemE {
    union {
        unsigned short x1[64 * XS1];   // 33792 B, edge_input bf16
        unsigned short h2[64 * HS];    // 17408 B (x1 dead after L1)
    } b0;
    unsigned short h1[64 * HS];        // 17408 B, H1 then H3
    float gate[64];
    int rows[64];
};

__global__ __launch_bounds__(256, 3) void edge_kernel(
    const float* __restrict__ coords, const int* __restrict__ eidx,
    const float* __restrict__ feat, const float* __restrict__ u,
    const unsigned short* __restrict__ frags,
    const float* __restrict__ eb1, const float* __restrict__ eb2,
    const float* __restrict__ eb3,
    const float* __restrict__ gb1, const float* __restrict__ gw2,
    const float* __restrict__ gb2,
    float* __restrict__ agg, float* __restrict__ deg) {
    __shared__ SmemE sm;
    int t = threadIdx.x;
    int wv = t >> 6;
    int lane = t & 63;
    int e0 = blockIdx.x * 64;

    {   // stage edge_input as bf16: 4 threads per edge
        int le = t >> 2, sub = t & 3;
        int e = e0 + le;
        int row = eidx[e];
        int col = eidx[N_EDGES + e];
        const float4* fi4 = (const float4*)(feat + row * CDIM);
        const float4* fj4 = (const float4*)(feat + col * CDIM);
        unsigned short* xr = sm.b0.x1 + le * XS1;
#pragma unroll
        for (int i = 0; i < 4; i++) {
            int c = sub * 16 + i * 4;
            float4 a = fi4[c >> 2];
            float4 b = fj4[c >> 2];
            float4 dd;
            dd.x = a.x - b.x; dd.y = a.y - b.y; dd.z = a.z - b.z; dd.w = a.w - b.w;
            *(ushort4*)(xr + c) = pack4(a);
            *(ushort4*)(xr + 64 + c) = pack4(b);
            *(ushort4*)(xr + 128 + c) = pack4(dd);
        }
        if (sub == 0) {
            sm.rows[le] = row;
            float xix = coords[row * 3], xiy = coords[row * 3 + 1], xiz = coords[row * 3 + 2];
            float xjx = coords[col * 3], xjy = coords[col * 3 + 1], xjz = coords[col * 3 + 2];
            float rx = xix - xjx, ry = xiy - xjy, rz = xiz - xjz;
            float ux = u[0], uy = u[1], uz = u[2];
            float4 sc;
            sc.x = rx * rx + ry * ry + rz * rz;
            sc.y = xix * ux + xiy * uy + xiz * uz;
            sc.z = xjx * ux + xjy * uy + xjz * uz;
            sc.w = rx * ux + ry * uy + rz * uz;
            *(ushort4*)(xr + 192) = pack4(sc);
            atomicAdd(&deg[row], 1.0f);
        } else if (sub == 3) {
            ushort4 z = {0, 0, 0, 0};
#pragma unroll
            for (int m = 0; m < 7; m++) *(ushort4*)(xr + 196 + m * 4) = z;  // pad K 196->224
        }
    }
    __syncthreads();

    floatx4 zero = {0.0f, 0.0f, 0.0f, 0.0f};
    floatx4 acc[8];

    // L1: edge_input (K=224) @ ew1 -> H1
#pragma unroll
    for (int ct = 0; ct < 8; ct++) acc[ct] = zero;
    mfma_layer<7>(sm.b0.x1 + wv * 16 * XS1, XS1, frags + F1_OFF, lane, acc);
    epilogue_store<true>(acc, eb1, sm.h1 + wv * 16 * HS, HS, lane);
    __syncthreads();

    // L2: H1 @ ew2 -> H2
#pragma unroll
    for (int ct = 0; ct < 8; ct++) acc[ct] = zero;
    mfma_layer<4>(sm.h1 + wv * 16 * HS, HS, frags + F2_OFF, lane, acc);
    epilogue_store<true>(acc, eb2, sm.b0.h2 + wv * 16 * HS, HS, lane);
    __syncthreads();

    // L3: H2 @ ew3 -> H3 (edge_hidden). Keep fp32 in regs for the message;
    // store bf16 copy for the gate GEMM.
    floatx4 h3[8];
#pragma unroll
    for (int ct = 0; ct < 8; ct++) h3[ct] = zero;
    mfma_layer<4>(sm.b0.h2 + wv * 16 * HS, HS, frags + F3_OFF, lane, h3);
    {
        int c = lane & 15;
#pragma unroll
        for (int ct = 0; ct < 8; ct++) {
            float b = eb3[ct * 16 + c];
#pragma unroll
            for (int i = 0; i < 4; i++) h3[ct][i] += b;
        }
    }
    epilogue_store<false>(h3, eb3 - 0, sm.h1 + wv * 16 * HS, HS, lane);  // bias already added; pass zero-bias below
    // NOTE: epilogue_store adds bias again — compensate by storing manually instead:
    __syncthreads();
    {   // overwrite with correct (single-bias) bf16 H3
        int q = lane >> 4, c = lane & 15;
        unsigned short* dst = sm.h1 + wv * 16 * HS;
#pragma unroll
        for (int ct = 0; ct < 8; ct++)
#pragma unroll
            for (int i = 0; i < 4; i++)
                dst[(q * 4 + i) * HS + ct * 16 + c] = f2bf(h3[ct][i]);
    }
    __syncthreads();

    // Gate: g1 = gelu(H3 @ gw1 + gb1); logit = g1 . gw2 + gb2
#pragma unroll
    for (int ct = 0; ct < 8; ct++) acc[ct] = zero;
    mfma_layer<4>(sm.h1 + wv * 16 * HS, HS, frags + FG_OFF, lane, acc);
    {
        int q = lane >> 4, c = lane & 15;
        float p[4] = {0.0f, 0.0f, 0.0f, 0.0f};
#pragma unroll
        for (int ct = 0; ct < 8; ct++) {
            int colc = ct * 16 + c;
            float b = gb1[colc];
            float w2 = gw2[colc];
#pragma unroll
            for (int i = 0; i < 4; i++) p[i] += gelu_exact(acc[ct][i] + b) * w2;
        }
#pragma unroll
        for (int i = 0; i < 4; i++) {
#pragma unroll
            for (int mask = 1; mask < 16; mask <<= 1) p[i] += __shfl_xor(p[i], mask, 64);
        }
        if (c == 0) {
            float gb = gb2[0];
#pragma unroll
            for (int i = 0; i < 4; i++) {
                float z = p[i] + gb;
                sm.gate[wv * 16 + q * 4 + i] = 1.0f / (1.0f + expf(-z));
            }
        }
    }
    __syncthreads();

    // Scatter msg = gate * h3 (fp32) into agg
    {
        int q = lane >> 4, c = lane & 15;
#pragma unroll
        for (int i = 0; i < 4; i++) {
            int e = wv * 16 + q * 4 + i;
            int row = sm.rows[e];
            float g = sm.gate[e];
            float* agr = agg + (long)row * MCDIM;
#pragma unroll
            for (int ct = 0; ct < 8; ct++) {
                atomicAdd(agr + ct * 16 + c, g * h3[ct][i]);
            }
        }
    }
}

// ---------------------------------------------------------------------------
// Global-context MLP (1 block, 64 threads) + tanh(res_scale)
// ---------------------------------------------------------------------------
__global__ void global_kernel(const float* __restrict__ gsum,
                              const float* __restrict__ glw1, const float* __restrict__ glb1,
                              const float* __restrict__ glw2, const float* __restrict__ glb2,
                              const float* __restrict__ glw3, const float* __restrict__ glb3,
                              const float* __restrict__ res_scale,
                              float* __restrict__ gctx, float* __restrict__ tres) {
    __shared__ float a[64], b[64];
    int t = threadIdx.x;
    a[t] = gsum[t] * (1.0f / (float)N_NODES);
    __syncthreads();
    float s = glb1[t];
    for (int k = 0; k < 64; k++) s += a[k] * glw1[k * 64 + t];
    b[t] = gelu_exact(s);
    __syncthreads();
    s = glb2[t];
    for (int k = 0; k < 64; k++) s += b[k] * glw2[k * 64 + t];
    __syncthreads();
    a[t] = gelu_exact(s);
    __syncthreads();
    s = glb3[t];
    for (int k = 0; k < 64; k++) s += a[k] * glw3[k * 64 + t];
    gctx[t] = s;
    if (t == 0) *tres = tanhf(res_scale[0]);
}

// ---------------------------------------------------------------------------
// fp32 register-tiled GEMM for the update MLP (unchanged from R1)
// ---------------------------------------------------------------------------
template <int K, bool GELU>
__device__ __forceinline__ void gemm128(const float* Xl, int xstride,
                                        const float* __restrict__ W,
                                        const float* __restrict__ bias,
                                        float* Yl, int ystride, int tx, int ty) {
    float acc[4][8];
#pragma unroll
    for (int i = 0; i < 4; i++)
#pragma unroll
        for (int j = 0; j < 8; j++) acc[i][j] = 0.0f;

    const float* xb = Xl + (ty * 4) * xstride;
#pragma unroll 2
    for (int k = 0; k < K; k++) {
        float xv[4];
        xv[0] = xb[k];
        xv[1] = xb[xstride + k];
        xv[2] = xb[2 * xstride + k];
        xv[3] = xb[3 * xstride + k];
        float4 wa = *(const float4*)(W + k * 128 + tx * 8);
        float4 wb = *(const float4*)(W + k * 128 + tx * 8 + 4);
        float wv[8] = {wa.x, wa.y, wa.z, wa.w, wb.x, wb.y, wb.z, wb.w};
#pragma unroll
        for (int i = 0; i < 4; i++)
#pragma unroll
            for (int j = 0; j < 8; j++) acc[i][j] += xv[i] * wv[j];
    }
#pragma unroll
    for (int i = 0; i < 4; i++) {
        float* yrow = Yl + (ty * 4 + i) * ystride + tx * 8;
#pragma unroll
        for (int j = 0; j < 8; j++) {
            float v = acc[i][j] + bias[tx * 8 + j];
            if (GELU) v = gelu_exact(v);
            yrow[j] = v;
        }
    }
}

struct SmemUpd {
    union {
        float ui[64 * USTRIDE];
        float hs2[64 * HSTRIDE];
    } a;
    float hs1[64 * HSTRIDE];
};

__global__ __launch_bounds__(256) void update_kernel(
    const float* __restrict__ feat, const float* __restrict__ agg,
    const float* __restrict__ deg, const float* __restrict__ gctx,
    const float* __restrict__ tres,
    const float* __restrict__ uw1, const float* __restrict__ ub1,
    const float* __restrict__ uw2, const float* __restrict__ ub2,
    const float* __restrict__ uw3, const float* __restrict__ ub3,
    float* __restrict__ out) {
    __shared__ SmemUpd sm;
    int t = threadIdx.x;
    int n0 = blockIdx.x * 64;

    {
        int ln = t >> 2, sub = t & 3;
        int n = n0 + ln;
        float* ur = sm.a.ui + ln * USTRIDE;
        if (n < N_NODES) {
            if (sub == 0) {
                const float4* f4 = (const float4*)(feat + n * CDIM);
#pragma unroll
                for (int m = 0; m < 16; m++) *(float4*)(ur + m * 4) = f4[m];
            } else if (sub == 3) {
                const float4* g4 = (const float4*)gctx;
#pragma unroll
                for (int m = 0; m < 16; m++) *(float4*)(ur + 192 + m * 4) = g4[m];
            } else {
                float inv = 1.0f / fmaxf(deg[n], 1.0f);
                const float4* a4 = (const float4*)(agg + (long)n * MCDIM + (sub - 1) * 64);
                float* dst = ur + sub * 64;
#pragma unroll
                for (int m = 0; m < 16; m++) {
                    float4 v = a4[m];
                    v.x *= inv; v.y *= inv; v.z *= inv; v.w *= inv;
                    *(float4*)(dst + m * 4) = v;
                }
            }
        } else {
            float4 z = {0.0f, 0.0f, 0.0f, 0.0f};
#pragma unroll
            for (int m = 0; m < 16; m++) *(float4*)(ur + sub * 64 + m * 4) = z;
        }
    }
    __syncthreads();

    int tx = t & 15, ty = t >> 4;
    gemm128<256, true>(sm.a.ui, USTRIDE, uw1, ub1, sm.hs1, HSTRIDE, tx, ty);
    __syncthreads();
    gemm128<128, true>(sm.hs1, HSTRIDE, uw2, ub2, sm.a.hs2, HSTRIDE, tx, ty);
    __syncthreads();

    {
        float acc[4][4];
#pragma unroll
        for (int i = 0; i < 4; i++)
#pragma unroll
            for (int j = 0; j < 4; j++) acc[i][j] = 0.0f;
        const float* xb = sm.a.hs2 + (ty * 4) * HSTRIDE;
#pragma unroll 2
        for (int k = 0; k < 128; k++) {
            float xv[4];
            xv[0] = xb[k];
            xv[1] = xb[HSTRIDE + k];
            xv[2] = xb[2 * HSTRIDE + k];
            xv[3] = xb[3 * HSTRIDE + k];
            float4 w = *(const float4*)(uw3 + k * 64 + tx * 4);
#pragma unroll
            for (int i = 0; i < 4; i++) {
                acc[i][0] += xv[i] * w.x;
                acc[i][1] += xv[i] * w.y;
                acc[i][2] += xv[i] * w.z;
                acc[i][3] += xv[i] * w.w;
            }
        }
        float tr = *tres;
        float4 bv = *(const float4*)(ub3 + tx * 4);
#pragma unroll
        for (int i = 0; i < 4; i++) {
            int n = n0 + ty * 4 + i;
            if (n < N_NODES) {
                float4 o;
                o.x = (acc[i][0] + bv.x) * tr;
                o.y = (acc[i][1] + bv.y) * tr;
                o.z = (acc[i][2] + bv.z) * tr;
                o.w = (acc[i][3] + bv.w) * tr;
                *(float4*)(out + (long)n * CDIM + tx * 4) = o;
            }
        }
    }
}

// ---------------------------------------------------------------------------
extern "C" void kernel_launch(void* const* d_in, const int* in_sizes, int n_in,
                              void* d_out, int out_size, void* d_ws, size_t ws_size,
                              hipStream_t stream) {
    const float* coords = (const float*)d_in[0];
    const float* h = (const float*)d_in[1];
    const float* flow = (const float*)d_in[2];
    const int* eidx = (const int*)d_in[3];
    const float* ln_g = (const float*)d_in[4];
    const float* ln_b = (const float*)d_in[5];
    const float* ew1 = (const float*)d_in[6];
    const float* eb1 = (const float*)d_in[7];
    const float* ew2 = (const float*)d_in[8];
    const float* eb2 = (const float*)d_in[9];
    const float* ew3 = (const float*)d_in[10];
    const float* eb3 = (const float*)d_in[11];
    const float* gw1 = (const float*)d_in[12];
    const float* gb1 = (const float*)d_in[13];
    const float* gw2 = (const float*)d_in[14];
    const float* gb2 = (const float*)d_in[15];
    const float* glw1 = (const float*)d_in[16];
    const float* glb1 = (const float*)d_in[17];
    const float* glw2 = (const float*)d_in[18];
    const float* glb2 = (const float*)d_in[19];
    const float* glw3 = (const float*)d_in[20];
    const float* glb3 = (const float*)d_in[21];
    const float* uw1 = (const float*)d_in[22];
    const float* ub1 = (const float*)d_in[23];
    const float* uw2 = (const float*)d_in[24];
    const float* ub2 = (const float*)d_in[25];
    const float* uw3 = (const float*)d_in[26];
    const float* ub3 = (const float*)d_in[27];
    const float* res = (const float*)d_in[28];

    unsigned short* frags = (unsigned short*)d_ws;   // FRAG_TOTAL ushorts = 155648 B
    float* wsf = (float*)d_ws;
    float* agg = wsf + (FRAG_TOTAL / 2);             // N*128
    float* deg = agg + (size_t)N_NODES * MCDIM;      // N
    float* gsum = deg + N_NODES;                     // 64
    float* feat = gsum + 64;                         // N*64
    float* u = feat + (size_t)N_NODES * CDIM;        // 4
    float* gctx = u + 4;                             // 64
    float* tres = gctx + 64;                         // 1

    hipMemsetAsync(agg, 0, ((size_t)N_NODES * 129 + 64) * sizeof(float), stream);
    prep_frags<<<(FRAG_TOTAL + 255) / 256, 256, 0, stream>>>(ew1, ew2, ew3, gw1, frags);
    ln_kernel<<<N_NODES / 4, 256, 0, stream>>>(h, ln_g, ln_b, flow, feat, gsum, u);
    edge_kernel<<<N_EDGES / 64, 256, 0, stream>>>(coords, eidx, feat, u, frags,
                                                  eb1, eb2, eb3, gb1, gw2, gb2, agg, deg);
    global_kernel<<<1, 64, 0, stream>>>(gsum, glw1, glb1, glw2, glb2, glw3, glb3,
                                        res, gctx, tres);
    update_kernel<<<(N_NODES + 63) / 64, 256, 0, stream>>>(feat, agg, deg, gctx, tres,
                                                           uw1, ub1, uw2, ub2, uw3, ub3,
                                                           (float*)d_out);
}

// Round 3
// 957.854 us; speedup vs baseline: 3.9956x; 1.2554x over previous
//
#include <hip/hip_runtime.h>
#include <math.h>

#define N_NODES 50000
#define N_EDGES 800000
#define CDIM 64
#define MCDIM 128

// bf16 LDS strides (elements). Row stride in dwords must be == 4 (mod 32) so
// ds_read_b128 A-fragment loads are at worst 2-way conflicted (free, m136).
#define XS1 264       // edge_input, K padded 196 -> 224 (132 dw % 32 == 4)
#define HS  136       // hidden layers, K=128       (68 dw % 32 == 4)
#define UST 264       // update_input, K=256 (+8 pad)

typedef __attribute__((ext_vector_type(8))) short short8;
typedef __attribute__((ext_vector_type(4))) float floatx4;

// A&S 7.1.26 erf (abs err 1.5e-7) -> exact-gelu to ~1e-7, ~14 VALU ops.
__device__ __forceinline__ float gelu_exact(float x) {
    float z = fabsf(x) * 0.70710678118654752f;
    float t = __builtin_amdgcn_rcpf(fmaf(0.3275911f, z, 1.0f));
    float poly = fmaf(fmaf(fmaf(fmaf(1.061405429f, t, -1.453152027f),
                                t, 1.421413741f),
                           t, -0.284496736f),
                      t, 0.254829592f) * t;
    float e = 1.0f - poly * __expf(-z * z);
    float s = copysignf(e, x);
    return 0.5f * x * (1.0f + s);
}

__device__ __forceinline__ unsigned short f2bf(float f) {  // RNE fp32->bf16
    unsigned int u = __float_as_uint(f);
    unsigned int r = u + 0x7fffu + ((u >> 16) & 1u);
    return (unsigned short)(r >> 16);
}
__device__ __forceinline__ float bf2f(unsigned short s) {
    return __uint_as_float(((unsigned int)s) << 16);
}
__device__ __forceinline__ ushort4 pack4(float4 v) {
    ushort4 r;
    r.x = f2bf(v.x); r.y = f2bf(v.y); r.z = f2bf(v.z); r.w = f2bf(v.w);
    return r;
}

// ---------------------------------------------------------------------------
// Weight fragment pre-swizzle. B-fragment for 16x16x32: lane l holds
// B[k = k0 + (l>>4)*8 + j][n = 16*ct + (l&15)], j=0..7 -> contiguous 16B/lane.
// ---------------------------------------------------------------------------
#define F1_OFF 0              // ew1: 7 chunks (K 196->224), N=128
#define F2_OFF (7 * 4096)     // ew2: 4
#define F3_OFF (11 * 4096)    // ew3: 4
#define FG_OFF (15 * 4096)    // gw1: 4
#define FU1_OFF (19 * 4096)   // uw1: 8 (K=256)
#define FU2_OFF (27 * 4096)   // uw2: 4
#define FU3_OFF (31 * 4096)   // uw3: 4 chunks x 2048 (N=64)
#define FRAG_TOTAL (31 * 4096 + 4 * 2048)

__global__ __launch_bounds__(256) void prep_frags(
    const float* __restrict__ ew1, const float* __restrict__ ew2,
    const float* __restrict__ ew3, const float* __restrict__ gw1,
    const float* __restrict__ uw1, const float* __restrict__ uw2,
    const float* __restrict__ uw3, unsigned short* __restrict__ frags) {
    int idx = blockIdx.x * 256 + threadIdx.x;
    if (idx >= FRAG_TOTAL) return;
    if (idx < FU3_OFF) {
        int chunk = idx >> 12;
        int rem = idx & 4095;
        int ct = rem >> 9;
        int lane = (rem >> 3) & 63;
        int j = rem & 7;
        const float* W; int K; int kbase;
        if (chunk < 7)       { W = ew1; K = 196; kbase = chunk * 32; }
        else if (chunk < 11) { W = ew2; K = 128; kbase = (chunk - 7) * 32; }
        else if (chunk < 15) { W = ew3; K = 128; kbase = (chunk - 11) * 32; }
        else if (chunk < 19) { W = gw1; K = 128; kbase = (chunk - 15) * 32; }
        else if (chunk < 27) { W = uw1; K = 256; kbase = (chunk - 19) * 32; }
        else                 { W = uw2; K = 128; kbase = (chunk - 27) * 32; }
        int k = kbase + (lane >> 4) * 8 + j;
        int n = ct * 16 + (lane & 15);
        frags[idx] = f2bf((k < K) ? W[k * 128 + n] : 0.0f);
    } else {  // uw3 [128][64]
        int rem = idx - FU3_OFF;
        int chunk = rem >> 11;
        int r = rem & 2047;
        int ct = r >> 9;
        int lane = (r >> 3) & 63;
        int j = r & 7;
        int k = chunk * 32 + (lane >> 4) * 8 + j;
        int n = ct * 16 + (lane & 15);
        frags[idx] = f2bf(uw3[k * 64 + n]);
    }
}

// ---------------------------------------------------------------------------
// MFMA layer over a 16-row LDS A-tile x (16*NCT) cols, K = 32*NCH.
// ---------------------------------------------------------------------------
template <int NCH, int NCT>
__device__ __forceinline__ void mfma_layer(const unsigned short* Xl, int xs,
                                           const unsigned short* __restrict__ F,
                                           int lane, floatx4* acc) {
    int q = lane >> 4, c = lane & 15;
    const unsigned short* xrow = Xl + c * xs + q * 8;
    for (int k0 = 0; k0 < NCH; k0++) {
        short8 a = *(const short8*)(xrow + k0 * 32);
#pragma unroll
        for (int ct = 0; ct < NCT; ct++) {
            short8 b = *(const short8*)(F + ((k0 * NCT + ct) * 64 + lane) * 8);
            acc[ct] = __builtin_amdgcn_mfma_f32_16x16x32_bf16(a, b, acc[ct], 0, 0, 0);
        }
    }
}

// bias + (opt) gelu, bf16 store into next layer's A-layout LDS tile.
// C layout: value (ct,i) at row (lane>>4)*4+i, col 16*ct+(lane&15).
template <bool GELU, int NCT>
__device__ __forceinline__ void epilogue_store(floatx4* acc,
                                               const float* __restrict__ bias,
                                               unsigned short* dst, int xs, int lane) {
    int q = lane >> 4, c = lane & 15;
#pragma unroll
    for (int ct = 0; ct < NCT; ct++) {
        float b = bias[ct * 16 + c];
#pragma unroll
        for (int i = 0; i < 4; i++) {
            float v = acc[ct][i] + b;
            if (GELU) v = gelu_exact(v);
            dst[(q * 4 + i) * xs + ct * 16 + c] = f2bf(v);
        }
    }
}

// ---------------------------------------------------------------------------
// LayerNorm + global-mean partials + flow_dir normalize + edge degree count
// ---------------------------------------------------------------------------
__global__ __launch_bounds__(256) void ln_count_kernel(
    const float* __restrict__ h, const float* __restrict__ ln_g,
    const float* __restrict__ ln_b, const float* __restrict__ flow_dir,
    const int* __restrict__ eidx, float* __restrict__ feat,
    float* __restrict__ gsum, float* __restrict__ u_out,
    int* __restrict__ deg_int) {
    int t = threadIdx.x;
    int ln = t >> 6;
    int c = t & 63;
    int n = blockIdx.x * 4 + ln;

    float x = h[n * CDIM + c];
    float s = x;
#pragma unroll
    for (int off = 32; off > 0; off >>= 1) s += __shfl_xor(s, off, 64);
    float mu = s * (1.0f / 64.0f);
    float d = x - mu;
    float v = d * d;
#pragma unroll
    for (int off = 32; off > 0; off >>= 1) v += __shfl_xor(v, off, 64);
    float rs = 1.0f / sqrtf(v * (1.0f / 64.0f) + 1e-5f);
    float f = d * rs * ln_g[c] + ln_b[c];
    feat[n * CDIM + c] = f;

    __shared__ float fs[4][64];
    fs[ln][c] = f;
    __syncthreads();
    if (t < 64) {
        float p = fs[0][t] + fs[1][t] + fs[2][t] + fs[3][t];
        atomicAdd(&gsum[t], p);
        int e = blockIdx.x * 64 + t;           // 12500*64 == N_EDGES
        atomicAdd(&deg_int[eidx[e]], 1);
    }
    if (blockIdx.x == 0 && t == 0) {
        float ux = flow_dir[0], uy = flow_dir[1], uz = flow_dir[2];
        float nrm = sqrtf(ux * ux + uy * uy + uz * uz) + 1e-8f;
        u_out[0] = ux / nrm;
        u_out[1] = uy / nrm;
        u_out[2] = uz / nrm;
    }
}

// ---------------------------------------------------------------------------
// Exclusive prefix scan of deg_int -> rowstart[0..N] and cursor[0..N)
// Single block, 1024 threads, 49 chunks.
// ---------------------------------------------------------------------------
__global__ __launch_bounds__(1024) void scan_kernel(
    const int* __restrict__ deg_int, int* __restrict__ rowstart,
    int* __restrict__ cursor) {
    __shared__ int wsum[16];
    __shared__ int run;
    int t = threadIdx.x;
    int wid = t >> 6, lane = t & 63;
    if (t == 0) run = 0;
    __syncthreads();
    for (int chunk = 0; chunk < 49; chunk++) {
        int i = chunk * 1024 + t;
        int v = (i < N_NODES) ? deg_int[i] : 0;
        int x = v;
#pragma unroll
        for (int off = 1; off < 64; off <<= 1) {
            int y = __shfl_up(x, off, 64);
            if (lane >= off) x += y;
        }
        if (lane == 63) wsum[wid] = x;
        __syncthreads();
        if (t < 16) {
            int sv = wsum[t];
#pragma unroll
            for (int off = 1; off < 16; off <<= 1) {
                int y = __shfl_up(sv, off, 16);
                if (t >= off) sv += y;
            }
            wsum[t] = sv;
        }
        __syncthreads();
        int wpre = (wid == 0) ? 0 : wsum[wid - 1];
        int excl = run + wpre + (x - v);
        if (i <= N_NODES) rowstart[i] = excl;
        if (i < N_NODES) cursor[i] = excl;
        __syncthreads();
        if (t == 0) run += wsum[15];
        __syncthreads();
    }
}

// ---------------------------------------------------------------------------
// Fused MFMA edge pipeline: 64 edges/block, 4 waves x 16 rows.
// use_msg: stream gated message rows to msg[pos[e]] (CSR slots);
// else fall back to atomic scatter into agg.
// ---------------------------------------------------------------------------
struct SmemE {
    union {
        unsigned short x1[64 * XS1];
        unsigned short h2[64 * HS];
    } b0;
    unsigned short h1[64 * HS];
    float gate[64];
    int pos[64];
    int rows[64];
};

__global__ __launch_bounds__(256, 3) void edge_kernel(
    const float* __restrict__ coords, const int* __restrict__ eidx,
    const float* __restrict__ feat, const float* __restrict__ u,
    const unsigned short* __restrict__ frags,
    const float* __restrict__ eb1, const float* __restrict__ eb2,
    const float* __restrict__ eb3,
    const float* __restrict__ gb1, const float* __restrict__ gw2,
    const float* __restrict__ gb2,
    int* __restrict__ cursor, unsigned short* __restrict__ msg,
    float* __restrict__ agg, int use_msg) {
    __shared__ SmemE sm;
    int t = threadIdx.x;
    int wv = t >> 6;
    int lane = t & 63;
    int e0 = blockIdx.x * 64;

    {   // stage edge_input as bf16: 4 threads per edge
        int le = t >> 2, sub = t & 3;
        int e = e0 + le;
        int row = eidx[e];
        int col = eidx[N_EDGES + e];
        const float4* fi4 = (const float4*)(feat + row * CDIM);
        const float4* fj4 = (const float4*)(feat + col * CDIM);
        unsigned short* xr = sm.b0.x1 + le * XS1;
#pragma unroll
        for (int i = 0; i < 4; i++) {
            int c = sub * 16 + i * 4;
            float4 a = fi4[c >> 2];
            float4 b = fj4[c >> 2];
            float4 dd;
            dd.x = a.x - b.x; dd.y = a.y - b.y; dd.z = a.z - b.z; dd.w = a.w - b.w;
            *(ushort4*)(xr + c) = pack4(a);
            *(ushort4*)(xr + 64 + c) = pack4(b);
            *(ushort4*)(xr + 128 + c) = pack4(dd);
        }
        if (sub == 0) {
            sm.rows[le] = row;
            sm.pos[le] = atomicAdd(&cursor[row], 1);  // cursor pre-seeded = rowstart
            float xix = coords[row * 3], xiy = coords[row * 3 + 1], xiz = coords[row * 3 + 2];
            float xjx = coords[col * 3], xjy = coords[col * 3 + 1], xjz = coords[col * 3 + 2];
            float rx = xix - xjx, ry = xiy - xjy, rz = xiz - xjz;
            float ux = u[0], uy = u[1], uz = u[2];
            float4 sc;
            sc.x = rx * rx + ry * ry + rz * rz;
            sc.y = xix * ux + xiy * uy + xiz * uz;
            sc.z = xjx * ux + xjy * uy + xjz * uz;
            sc.w = rx * ux + ry * uy + rz * uz;
            *(ushort4*)(xr + 192) = pack4(sc);
        } else if (sub == 3) {
            ushort4 z = {0, 0, 0, 0};
#pragma unroll
            for (int m = 0; m < 7; m++) *(ushort4*)(xr + 196 + m * 4) = z;
        }
    }
    __syncthreads();

    floatx4 zero = {0.0f, 0.0f, 0.0f, 0.0f};
    floatx4 acc[8];

    // L1
#pragma unroll
    for (int ct = 0; ct < 8; ct++) acc[ct] = zero;
    mfma_layer<7, 8>(sm.b0.x1 + wv * 16 * XS1, XS1, frags + F1_OFF, lane, acc);
    epilogue_store<true, 8>(acc, eb1, sm.h1 + wv * 16 * HS, HS, lane);
    __syncthreads();

    // L2
#pragma unroll
    for (int ct = 0; ct < 8; ct++) acc[ct] = zero;
    mfma_layer<4, 8>(sm.h1 + wv * 16 * HS, HS, frags + F2_OFF, lane, acc);
    epilogue_store<true, 8>(acc, eb2, sm.b0.h2 + wv * 16 * HS, HS, lane);
    __syncthreads();

    // L3 -> h3 kept fp32 in regs, bf16 copy to LDS for the gate GEMM
    floatx4 h3[8];
#pragma unroll
    for (int ct = 0; ct < 8; ct++) h3[ct] = zero;
    mfma_layer<4, 8>(sm.b0.h2 + wv * 16 * HS, HS, frags + F3_OFF, lane, h3);
    {
        int q = lane >> 4, c = lane & 15;
        unsigned short* dst = sm.h1 + wv * 16 * HS;
#pragma unroll
        for (int ct = 0; ct < 8; ct++) {
            float b = eb3[ct * 16 + c];
#pragma unroll
            for (int i = 0; i < 4; i++) {
                h3[ct][i] += b;
                dst[(q * 4 + i) * HS + ct * 16 + c] = f2bf(h3[ct][i]);
            }
        }
    }
    __syncthreads();

    // Gate
#pragma unroll
    for (int ct = 0; ct < 8; ct++) acc[ct] = zero;
    mfma_layer<4, 8>(sm.h1 + wv * 16 * HS, HS, frags + FG_OFF, lane, acc);
    {
        int q = lane >> 4, c = lane & 15;
        float p[4] = {0.0f, 0.0f, 0.0f, 0.0f};
#pragma unroll
        for (int ct = 0; ct < 8; ct++) {
            int colc = ct * 16 + c;
            float b = gb1[colc];
            float w2 = gw2[colc];
#pragma unroll
            for (int i = 0; i < 4; i++) p[i] += gelu_exact(acc[ct][i] + b) * w2;
        }
#pragma unroll
        for (int i = 0; i < 4; i++) {
#pragma unroll
            for (int mask = 1; mask < 16; mask <<= 1) p[i] += __shfl_xor(p[i], mask, 64);
        }
        if (c == 0) {
            float gb = gb2[0];
#pragma unroll
            for (int i = 0; i < 4; i++) {
                float z = p[i] + gb;
                sm.gate[wv * 16 + q * 4 + i] = 1.0f / (1.0f + __expf(-z));
            }
        }
    }
    __syncthreads();

    if (use_msg) {
        // scaled bf16 message back to LDS (C->row layout transform) ...
        {
            int q = lane >> 4, c = lane & 15;
            unsigned short* dst = sm.h1 + wv * 16 * HS;
            float gv[4];
#pragma unroll
            for (int i = 0; i < 4; i++) gv[i] = sm.gate[wv * 16 + q * 4 + i];
#pragma unroll
            for (int ct = 0; ct < 8; ct++)
#pragma unroll
                for (int i = 0; i < 4; i++)
                    dst[(q * 4 + i) * HS + ct * 16 + c] = f2bf(h3[ct][i] * gv[i]);
        }
        __syncthreads();
        // ... then coalesced 256B-row stream to msg[pos[e]]
        {
            int le = t >> 2, sub = t & 3;
            long base = (long)sm.pos[le] * MCDIM;
            const unsigned short* src = sm.h1 + le * HS;
#pragma unroll
            for (int m = 0; m < 4; m++) {
                int off = m * 32 + sub * 8;
                *(short8*)(msg + base + off) = *(const short8*)(src + off);
            }
        }
    } else {
        int q = lane >> 4, c = lane & 15;
#pragma unroll
        for (int i = 0; i < 4; i++) {
            int e = wv * 16 + q * 4 + i;
            int row = sm.rows[e];
            float g = sm.gate[e];
            float* agr = agg + (long)row * MCDIM;
#pragma unroll
            for (int ct = 0; ct < 8; ct++)
                atomicAdd(agr + ct * 16 + c, g * h3[ct][i]);
        }
    }
}

// ---------------------------------------------------------------------------
// Global-context MLP (1 block, 64 threads) + tanh(res_scale)
// ---------------------------------------------------------------------------
__global__ void global_kernel(const float* __restrict__ gsum,
                              const float* __restrict__ glw1, const float* __restrict__ glb1,
                              const float* __restrict__ glw2, const float* __restrict__ glb2,
                              const float* __restrict__ glw3, const float* __restrict__ glb3,
                              const float* __restrict__ res_scale,
                              float* __restrict__ gctx, float* __restrict__ tres) {
    __shared__ float a[64], b[64];
    int t = threadIdx.x;
    a[t] = gsum[t] * (1.0f / (float)N_NODES);
    __syncthreads();
    float s = glb1[t];
    for (int k = 0; k < 64; k++) s += a[k] * glw1[k * 64 + t];
    b[t] = gelu_exact(s);
    __syncthreads();
    s = glb2[t];
    for (int k = 0; k < 64; k++) s += b[k] * glw2[k * 64 + t];
    __syncthreads();
    a[t] = gelu_exact(s);
    __syncthreads();
    s = glb3[t];
    for (int k = 0; k < 64; k++) s += a[k] * glw3[k * 64 + t];
    gctx[t] = s;
    if (t == 0) *tres = tanhf(res_scale[0]);
}

// ---------------------------------------------------------------------------
// MFMA node update: gather+avg messages, [feat|agg|gctx] (K=256) -> 3 layers
// 64 nodes/block, 4 waves x 16 rows.
// ---------------------------------------------------------------------------
struct SmemU {
    union {
        unsigned short ui[64 * UST];
        unsigned short h2[64 * HS];
    } b0;
    unsigned short h1[64 * HS];
};

__global__ __launch_bounds__(256, 3) void update_kernel(
    const float* __restrict__ feat, const int* __restrict__ rowstart,
    const unsigned short* __restrict__ msg, const float* __restrict__ agg,
    const float* __restrict__ gctx, const float* __restrict__ tres,
    const unsigned short* __restrict__ frags,
    const float* __restrict__ ub1, const float* __restrict__ ub2,
    const float* __restrict__ ub3, int use_msg,
    float* __restrict__ out) {
    __shared__ SmemU sm;
    int t = threadIdx.x;
    int wv = t >> 6;
    int lane = t & 63;
    int n0 = blockIdx.x * 64;

    {   // stage update_input row (256 bf16): 4 threads/node
        int ln = t >> 2, sub = t & 3;
        int n = n0 + ln;
        unsigned short* ur = sm.b0.ui + ln * UST;
        if (n < N_NODES) {
            const float4* f4 = (const float4*)(feat + n * CDIM + sub * 16);
            const float4* g4 = (const float4*)(gctx + sub * 16);
#pragma unroll
            for (int m = 0; m < 4; m++) {
                *(ushort4*)(ur + sub * 16 + m * 4) = pack4(f4[m]);
                *(ushort4*)(ur + 192 + sub * 16 + m * 4) = pack4(g4[m]);
            }
            int rs = rowstart[n], re = rowstart[n + 1];
            float accv[32];
#pragma unroll
            for (int k = 0; k < 32; k++) accv[k] = 0.0f;
            if (use_msg) {
                for (int s = rs; s < re; s++) {
                    const short8* mrow = (const short8*)(msg + (long)s * MCDIM + sub * 32);
#pragma unroll
                    for (int m = 0; m < 4; m++) {
                        short8 v = mrow[m];
#pragma unroll
                        for (int j = 0; j < 8; j++)
                            accv[m * 8 + j] += bf2f((unsigned short)v[j]);
                    }
                }
            } else {
                const float* arow = agg + (long)n * MCDIM + sub * 32;
#pragma unroll
                for (int k = 0; k < 32; k++) accv[k] = arow[k];
            }
            float inv = 1.0f / fmaxf((float)(re - rs), 1.0f);
#pragma unroll
            for (int k = 0; k < 32; k++) ur[64 + sub * 32 + k] = f2bf(accv[k] * inv);
        } else {
            ushort4 z = {0, 0, 0, 0};
#pragma unroll
            for (int m = 0; m < 16; m++) *(ushort4*)(ur + sub * 64 + m * 4) = z;
        }
    }
    __syncthreads();

    floatx4 zero = {0.0f, 0.0f, 0.0f, 0.0f};
    floatx4 acc[8];
#pragma unroll
    for (int ct = 0; ct < 8; ct++) acc[ct] = zero;
    mfma_layer<8, 8>(sm.b0.ui + wv * 16 * UST, UST, frags + FU1_OFF, lane, acc);
    epilogue_store<true, 8>(acc, ub1, sm.h1 + wv * 16 * HS, HS, lane);
    __syncthreads();

#pragma unroll
    for (int ct = 0; ct < 8; ct++) acc[ct] = zero;
    mfma_layer<4, 8>(sm.h1 + wv * 16 * HS, HS, frags + FU2_OFF, lane, acc);
    epilogue_store<true, 8>(acc, ub2, sm.b0.h2 + wv * 16 * HS, HS, lane);
    __syncthreads();

    floatx4 acc3[4];
#pragma unroll
    for (int ct = 0; ct < 4; ct++) acc3[ct] = zero;
    mfma_layer<4, 4>(sm.b0.h2 + wv * 16 * HS, HS, frags + FU3_OFF, lane, acc3);
    {
        int q = lane >> 4, c = lane & 15;
        float tr = *tres;
#pragma unroll
        for (int ct = 0; ct < 4; ct++) {
            float b = ub3[ct * 16 + c];
#pragma unroll
            for (int i = 0; i < 4; i++) {
                int n = n0 + wv * 16 + q * 4 + i;
                if (n < N_NODES) out[(long)n * CDIM + ct * 16 + c] = (acc3[ct][i] + b) * tr;
            }
        }
    }
}

// ---------------------------------------------------------------------------
extern "C" void kernel_launch(void* const* d_in, const int* in_sizes, int n_in,
                              void* d_out, int out_size, void* d_ws, size_t ws_size,
                              hipStream_t stream) {
    const float* coords = (const float*)d_in[0];
    const float* h = (const float*)d_in[1];
    const float* flow = (const float*)d_in[2];
    const int* eidx = (const int*)d_in[3];
    const float* ln_g = (const float*)d_in[4];
    const float* ln_b = (const float*)d_in[5];
    const float* ew1 = (const float*)d_in[6];
    const float* eb1 = (const float*)d_in[7];
    const float* ew2 = (const float*)d_in[8];
    const float* eb2 = (const float*)d_in[9];
    const float* ew3 = (const float*)d_in[10];
    const float* eb3 = (const float*)d_in[11];
    const float* gw1 = (const float*)d_in[12];
    const float* gb1 = (const float*)d_in[13];
    const float* gw2 = (const float*)d_in[14];
    const float* gb2 = (const float*)d_in[15];
    const float* glw1 = (const float*)d_in[16];
    const float* glb1 = (const float*)d_in[17];
    const float* glw2 = (const float*)d_in[18];
    const float* glb2 = (const float*)d_in[19];
    const float* glw3 = (const float*)d_in[20];
    const float* glb3 = (const float*)d_in[21];
    const float* uw1 = (const float*)d_in[22];
    const float* ub1 = (const float*)d_in[23];
    const float* uw2 = (const float*)d_in[24];
    const float* ub2 = (const float*)d_in[25];
    const float* uw3 = (const float*)d_in[26];
    const float* ub3 = (const float*)d_in[27];
    const float* res = (const float*)d_in[28];

    // ---- workspace carve-up ----
    char* base = (char*)d_ws;
    unsigned short* frags = (unsigned short*)base;              // FRAG_TOTAL
    float* feat = (float*)(base + FRAG_TOTAL * 2);              // N*64
    float* gsum = feat + (size_t)N_NODES * CDIM;                // 64
    float* u = gsum + 64;                                       // 4
    float* gctx = u + 4;                                        // 64
    float* tres = gctx + 64;                                    // 1
    int* rowstart = (int*)(tres + 1);                           // N+1
    int* cursor = rowstart + (N_NODES + 1);                     // N
    int* deg_int = cursor + N_NODES;                            // N
    char* tail = (char*)(deg_int + N_NODES);
    tail = (char*)(((uintptr_t)tail + 255) & ~(uintptr_t)255);
    size_t head_bytes = (size_t)(tail - base);
    size_t msg_bytes = (size_t)N_EDGES * MCDIM * 2;             // 204.8 MB bf16
    int use_msg = (ws_size >= head_bytes + msg_bytes) ? 1 : 0;
    unsigned short* msg = (unsigned short*)tail;                // CSR slots
    float* agg = (float*)tail;                                  // fallback (25.6 MB)

    hipMemsetAsync(gsum, 0, (64 + 4 + 64 + 1) * sizeof(float), stream);
    hipMemsetAsync(deg_int, 0, N_NODES * sizeof(int), stream);
    if (!use_msg)
        hipMemsetAsync(agg, 0, (size_t)N_NODES * MCDIM * sizeof(float), stream);

    prep_frags<<<(FRAG_TOTAL + 255) / 256, 256, 0, stream>>>(ew1, ew2, ew3, gw1,
                                                             uw1, uw2, uw3, frags);
    ln_count_kernel<<<N_NODES / 4, 256, 0, stream>>>(h, ln_g, ln_b, flow, eidx,
                                                     feat, gsum, u, deg_int);
    scan_kernel<<<1, 1024, 0, stream>>>(deg_int, rowstart, cursor);
    edge_kernel<<<N_EDGES / 64, 256, 0, stream>>>(coords, eidx, feat, u, frags,
                                                  eb1, eb2, eb3, gb1, gw2, gb2,
                                                  cursor, msg, agg, use_msg);
    global_kernel<<<1, 64, 0, stream>>>(gsum, glw1, glb1, glw2, glb2, glw3, glb3,
                                        res, gctx, tres);
    update_kernel<<<(N_NODES + 63) / 64, 256, 0, stream>>>(feat, rowstart, msg, agg,
                                                           gctx, tres, frags,
                                                           ub1, ub2, ub3, use_msg,
                                                           (float*)d_out);
}